// Round 6
// baseline (158.694 us; speedup 1.0000x reference)
//
#include <hip/hip_runtime.h>
#include <math.h>

// YOLO box decode: (32, 3*85, 52, 52) -> (32*3*52*52, 85)
// Per-WAVE LDS transpose with PERSISTENT waves + 2-deep software pipeline:
// each wave owns a private 16x85 LDS slice and processes exactly 4 tiles.
// Loads for tile i+1 are issued before the LDS/store phase of tile i, so
// reads stay in flight across the store phase (R5 post-mortem: the per-wave
// full drain -- load burst, dead LDS phase, store burst -- was the limiter;
// R2 and R5 both plateaued at ~53 us despite different granules/barriers).
// Loads are CACHED (harness d2d-restores input -> L3-warm; NT loads forfeit
// that). Stores stay non-temporal (write-once stream, keep L3 for reads).
// Correctness: s_waitcnt lgkmcnt(0) + memory clobber between ds_writes and
// the b128 read-back (intra-wave LDS RAW, R3 race); compiler barrier at loop
// end pins ds_read(i) before ds_write(i+1) (DS pipe is in-order per wave).

typedef float nat_float4 __attribute__((ext_vector_type(4)));

#define NSPAT   2704          // 52*52
#define NCH     85            // 5 + 80 classes
#define WTILE_S 16            // spatial positions per wave-tile
#define WITEMS  340           // float4 items per tile = 16*85/4
#define NSLOTS  6             // ceil(340/64)
#define WPB     4             // waves per block (256 threads)
#define TILES_PER_SLAB 169    // 2704/16
#define TOTAL_TILES    16224  // 96 slabs * 169
#define NBLOCKS 1014          // ~4 blocks/CU, fully resident
#define NWAVES  (NBLOCKS * WPB)   // 4056 -> exactly 4 tiles per wave
#define TPW     4

__global__ __launch_bounds__(256) void yolo_decode_kernel(
    const float* __restrict__ in, float* __restrict__ out) {
  __shared__ __align__(16) float tile[WPB][WTILE_S * NCH];  // 21760 B/block

  const int lane = threadIdx.x & 63;
  const int widx = threadIdx.x >> 6;
  float* slice = tile[widx];
  const int gw0 = blockIdx.x * WPB + widx;   // first tile of this wave

  nat_float4 v[2][NSLOTS];                   // double-buffered load slots

  // ---- prefetch tile 0 ----
  {
    const int t    = gw0;
    const int slab = t / TILES_PER_SLAB;
    const int tt   = t - slab * TILES_PER_SLAB;
    const float* src = in + (long)slab * (NCH * NSPAT) + tt * WTILE_S;
    #pragma unroll
    for (int k = 0; k < NSLOTS; ++k) {
      const int idx = lane + 64 * k;
      if (idx < WITEMS) {
        const int c = idx >> 2, q = idx & 3;
        v[0][k] = *(const nat_float4*)(src + c * NSPAT + 4 * q);
      }
    }
  }

  #pragma unroll
  for (int i = 0; i < TPW; ++i) {
    // ---- issue loads for tile i+1 FIRST (stay in flight across store phase)
    if (i + 1 < TPW) {
      const int tn   = gw0 + (i + 1) * NWAVES;
      const int slab = tn / TILES_PER_SLAB;
      const int tt   = tn - slab * TILES_PER_SLAB;
      const float* src = in + (long)slab * (NCH * NSPAT) + tt * WTILE_S;
      #pragma unroll
      for (int k = 0; k < NSLOTS; ++k) {
        const int idx = lane + 64 * k;
        if (idx < WITEMS) {
          const int c = idx >> 2, q = idx & 3;
          v[(i + 1) & 1][k] = *(const nat_float4*)(src + c * NSPAT + 4 * q);
        }
      }
    }

    // ---- transform tile i + stage to private LDS slice (output layout) ----
    const int t    = gw0 + i * NWAVES;
    const int slab = t / TILES_PER_SLAB;
    const int tt   = t - slab * TILES_PER_SLAB;
    const int a    = slab % 3;                       // ANCHOR_MASK = [0,1,2]
    const float aw = (a == 0) ? 10.0f : (a == 1) ? 16.0f : 33.0f;
    const float ah = (a == 0) ? 13.0f : (a == 1) ? 30.0f : 23.0f;
    const long base = (long)slab * (NCH * NSPAT);
    const int s0   = tt * WTILE_S;

    #pragma unroll
    for (int k = 0; k < NSLOTS; ++k) {
      const int idx = lane + 64 * k;
      if (idx < WITEMS) {
        const int c = idx >> 2, q = idx & 3;
        float e[4] = {v[i & 1][k].x, v[i & 1][k].y, v[i & 1][k].z, v[i & 1][k].w};
        if (c < 5) {               // only lanes 0..19 of slot 0 diverge
          #pragma unroll
          for (int j = 0; j < 4; ++j) {
            const int sg = s0 + 4 * q + j;   // global spatial index: h*52 + w
            float x = e[j];
            if (c == 0)      x = 1.0f / (1.0f + __expf(-x)) + (float)(sg % 52);
            else if (c == 1) x = 1.0f / (1.0f + __expf(-x)) + (float)(sg / 52);
            else if (c == 2) x = __expf(x * (1.0f / 416.0f)) * aw;
            else if (c == 3) x = __expf(x * (1.0f / 416.0f)) * ah;
            else             x = 1.0f / (1.0f + __expf(-x));
            e[j] = x;
          }
        }
        #pragma unroll
        for (int j = 0; j < 4; ++j)
          slice[(4 * q + j) * NCH + c] = e[j];   // ~2-3-way bank aliasing: free
      }
    }

    // intra-wave LDS RAW: all ds_writes must complete before b128 read-back
    asm volatile("s_waitcnt lgkmcnt(0)" ::: "memory");

    // ---- contiguous NT float4 write-out of this tile's 1360 floats ----
    const nat_float4* s4 = (const nat_float4*)slice;
    nat_float4* dst = (nat_float4*)(out + base + s0 * NCH);  // 16B-aligned
    #pragma unroll
    for (int k = 0; k < NSLOTS; ++k) {
      const int idx = lane + 64 * k;
      if (idx < WITEMS) __builtin_nontemporal_store(s4[idx], dst + idx);
    }

    // pin ds_read(i) before ds_write(i+1); HW DS pipe is in-order per wave
    asm volatile("" ::: "memory");
  }
}

extern "C" void kernel_launch(void* const* d_in, const int* in_sizes, int n_in,
                              void* d_out, int out_size, void* d_ws, size_t ws_size,
                              hipStream_t stream) {
  const float* in = (const float*)d_in[0];
  float* out = (float*)d_out;
  yolo_decode_kernel<<<NBLOCKS, 256, 0, stream>>>(in, out);
}